// Round 4
// baseline (246.490 us; speedup 1.0000x reference)
//
#include <hip/hip_runtime.h>
#include <math.h>

// Problem constants: BSZ=64, BEAM=8, VOCAB=50257, STEP=5
#define BSZ   64
#define BEAM  8
#define VOCAB 50257
#define NSTEP 5
#define K     16
#define DIV_RATE 0.5f
#define SPLIT 8
#define N4    (VOCAB / 4)                  // 12564 float4s (+1 tail elem)
#define F4SEG ((N4 + SPLIT - 1) / SPLIT)   // 1571 float4 per segment
#define ROWCAP 1024                        // per-row candidate cap (R3 passed @512)

typedef unsigned long long u64;
typedef unsigned u32;

// order-preserving float<->uint (monotone for all non-NaN)
__device__ __forceinline__ u32 f2s(float f) {
    u32 u = __float_as_uint(f);
    return (u & 0x80000000u) ? ~u : (u | 0x80000000u);
}
__device__ __forceinline__ float s2f(u32 s) {
    u32 u = (s & 0x80000000u) ? (s ^ 0x80000000u) : ~s;
    return __uint_as_float(u);
}

// wave(64)-wide max of a u64 key
__device__ __forceinline__ u64 wmax64(u64 k) {
#pragma unroll
    for (int off = 32; off > 0; off >>= 1) {
        u32 lo = __shfl_xor((u32)k, off, 64);
        u32 hi = __shfl_xor((u32)(k >> 32), off, 64);
        u64 o = ((u64)hi << 32) | lo;
        if (o > k) k = o;
    }
    return k;
}

// full bitonic sort of one u32 per lane across the 64-lane wave, ASCENDING
// (validated in R3: absmax 0). 21 compare-exchange steps.
__device__ __forceinline__ u32 bitonic64_asc(u32 v, int lane) {
#define BSTEP(K_, J_)                                                        \
    {                                                                        \
        u32 o = __shfl_xor(v, (J_), 64);                                     \
        bool tmin = ((lane & (J_)) == 0) == ((lane & (K_)) == 0);            \
        v = tmin ? (v < o ? v : o) : (v > o ? v : o);                        \
    }
    BSTEP(2, 1)
    BSTEP(4, 2)  BSTEP(4, 1)
    BSTEP(8, 4)  BSTEP(8, 2)  BSTEP(8, 1)
    BSTEP(16, 8) BSTEP(16, 4) BSTEP(16, 2) BSTEP(16, 1)
    BSTEP(32, 16) BSTEP(32, 8) BSTEP(32, 4) BSTEP(32, 2) BSTEP(32, 1)
    BSTEP(64, 32) BSTEP(64, 16) BSTEP(64, 8) BSTEP(64, 4) BSTEP(64, 2) BSTEP(64, 1)
#undef BSTEP
    return v;
}

// Phase 1: per (row, segment): T = exact 16th largest of the 256 per-thread
// maxima (=> T <= 16th largest element of the segment, and exactly the 16
// threads with max >= T can own candidates). Those <=16 threads re-load their
// 28 elements (L2-hot, ~1.8 KB/block) and append elems >= T directly to the
// row's global candidate buffer. Single effective global pass.
__global__ __launch_bounds__(256) void collect(
    const float* __restrict__ lprobs, u64* __restrict__ rowbuf,
    int* __restrict__ rowcnt)
{
    const int tid  = threadIdx.x;
    const int lane = tid & 63;
    const int wave = tid >> 6;
    const int seg  = blockIdx.x;     // 0..7
    const int row  = blockIdx.y;     // 0..511

    const int s0 = seg * F4SEG;
    const int s1 = min(N4, s0 + F4SEG);
    const float4* rp4 = (const float4*)(lprobs + (size_t)row * VOCAB);

    // ---- pass 1: per-thread max only (values are NOT kept live) ----
    float m = -INFINITY;
#pragma unroll
    for (int k = 0; k < 7; ++k) {
        int p = s0 + k * 256 + tid;
        if (p < s1) {
            float4 v = rp4[p];
            m = fmaxf(m, fmaxf(fmaxf(v.x, v.y), fmaxf(v.z, v.w)));
        }
    }
    if (seg == SPLIT - 1 && tid == 0)
        m = fmaxf(m, ((const float*)rp4)[VOCAB - 1]);   // tail elem 50256

    // ---- threshold: 16th largest of the 256 maxima ----
    __shared__ u32 smax[64];        // the 4 waves' top-16 maxima
    u32 v0 = bitonic64_asc(f2s(m), lane);
    if (lane >= 48) smax[wave * 16 + (lane - 48)] = v0;
    __syncthreads();
    // all 4 waves redundantly sort the 64 survivors (no wave0 serialization)
    u32 w0 = bitonic64_asc(smax[lane], lane);
    const float T = s2f(__shfl(w0, 48, 64));    // lane 48 = 16th largest

    // ---- re-scan: only the (exactly) 16 threads with m >= T participate ----
    if (m >= T) {
#pragma unroll
        for (int k = 0; k < 7; ++k) {
            int p = s0 + k * 256 + tid;
            if (p < s1) {
                float4 v = rp4[p];
                int b4 = 4 * p;
                if (v.x >= T) { int g = atomicAdd(&rowcnt[row], 1); if (g < ROWCAP) rowbuf[(size_t)row * ROWCAP + g] = ((u64)f2s(v.x) << 32) | (u32)~(u32)(b4 + 0); }
                if (v.y >= T) { int g = atomicAdd(&rowcnt[row], 1); if (g < ROWCAP) rowbuf[(size_t)row * ROWCAP + g] = ((u64)f2s(v.y) << 32) | (u32)~(u32)(b4 + 1); }
                if (v.z >= T) { int g = atomicAdd(&rowcnt[row], 1); if (g < ROWCAP) rowbuf[(size_t)row * ROWCAP + g] = ((u64)f2s(v.z) << 32) | (u32)~(u32)(b4 + 2); }
                if (v.w >= T) { int g = atomicAdd(&rowcnt[row], 1); if (g < ROWCAP) rowbuf[(size_t)row * ROWCAP + g] = ((u64)f2s(v.w) << 32) | (u32)~(u32)(b4 + 3); }
            }
        }
        if (seg == SPLIT - 1 && tid == 0) {
            float e = ((const float*)rp4)[VOCAB - 1];
            if (e >= T) { int g = atomicAdd(&rowcnt[row], 1); if (g < ROWCAP) rowbuf[(size_t)row * ROWCAP + g] = ((u64)f2s(e) << 32) | (u32)~(u32)(VOCAB - 1); }
        }
    }
}

// Phase 2: block b (of 64), wave j: exact sorted top-16 of row (b,j)'s
// candidate list (16 rounds of reg-max + wave-argmax); bias + sibling
// penalty; wave 0 selects the final top-16 of 128. (Candidate order in
// rowbuf is nondeterministic, but keys are unique => output deterministic.)
__global__ __launch_bounds__(512) void merge_final(
    const u64* __restrict__ rowbuf, const int* __restrict__ rowcnt,
    const float* __restrict__ scores, const int* __restrict__ step_ptr,
    float* __restrict__ out)
{
    const int tid  = threadIdx.x;
    const int lane = tid & 63;
    const int j    = tid >> 6;       // beam 0..7
    const int b    = blockIdx.x;
    const int row  = b * BEAM + j;
    const int step = *step_ptr;

    __shared__ u64 rowkey[BEAM * K];
    __shared__ int rowvidx[BEAM * K];

    const int n = min(rowcnt[row], ROWCAP);
    u64 k[16];
#pragma unroll
    for (int i = 0; i < 16; ++i) {
        int p = lane + 64 * i;
        k[i] = (p < n) ? rowbuf[(size_t)row * ROWCAP + p] : 0ull;
    }

    u64 mine = 0;
#pragma unroll 1
    for (int it = 0; it < K; ++it) {
        u64 lm = k[0];
#pragma unroll
        for (int i = 1; i < 16; ++i) lm = (k[i] > lm) ? k[i] : lm;
        u64 mm = wmax64(lm);
        if (lane == it) mine = mm;
#pragma unroll
        for (int i = 0; i < 16; ++i) if (k[i] == mm) k[i] = 0;
    }

    float* out_s = out;
    float* out_i = out + BSZ * K;
    float* out_b = out + 2 * BSZ * K;

    if (step == 0) {
        // reference: top_k(lprobs[:,0,:]): idx%vocab=idx, idx//vocab=0
        if (j == 0 && lane < K) {
            out_s[b * K + lane] = s2f((u32)(mine >> 32));
            out_i[b * K + lane] = (float)(int)~(u32)mine;
            out_b[b * K + lane] = 0.0f;
        }
        return;
    }

    if (lane < K) {
        float v   = s2f((u32)(mine >> 32));
        float add = scores[row * NSTEP + step - 1];
        float sc  = v + add - (float)(lane + 1) * DIV_RATE;   // rank = lane
        int c = j * K + lane;
        rowkey[c]  = ((u64)f2s(sc) << 32) | (u32)(127 - c);   // lower c wins ties
        rowvidx[c] = (int)~(u32)mine;
    }
    __syncthreads();

    if (tid < 64) {
        u64 pa = rowkey[lane];
        u64 pb = rowkey[lane + 64];
        u64 m2 = 0;
#pragma unroll 1
        for (int it = 0; it < K; ++it) {
            u64 mm = wmax64(pa > pb ? pa : pb);
            if (lane == it) m2 = mm;
            if (pa == mm) pa = 0; else if (pb == mm) pb = 0;
        }
        if (lane < K) {
            int c = 127 - (int)(m2 & 0xFFFFFFFFull);
            out_s[b * K + lane] = s2f((u32)(m2 >> 32));
            out_i[b * K + lane] = (float)rowvidx[c];
            out_b[b * K + lane] = (float)(c >> 4);
        }
    }
}

extern "C" void kernel_launch(void* const* d_in, const int* in_sizes, int n_in,
                              void* d_out, int out_size, void* d_ws, size_t ws_size,
                              hipStream_t stream) {
    const float* lprobs = (const float*)d_in[0];
    const float* scores = (const float*)d_in[1];
    const int*   step   = (const int*)d_in[2];

    // ws layout: [0,4KB) row counters (512 ints), then row candidate buffers
    int* rowcnt = (int*)d_ws;
    u64* rowbuf = (u64*)((char*)d_ws + 4096);   // 512 * 1024 * 8 B = 4 MB

    hipMemsetAsync(d_ws, 0, 4096, stream);
    dim3 g1(SPLIT, BSZ * BEAM);
    collect<<<g1, 256, 0, stream>>>(lprobs, rowbuf, rowcnt);
    merge_final<<<BSZ, 512, 0, stream>>>(rowbuf, rowcnt, scores, step,
                                         (float*)d_out);
}

// Round 5
// 186.307 us; speedup vs baseline: 1.3230x; 1.3230x over previous
//
#include <hip/hip_runtime.h>
#include <math.h>

// Problem constants: BSZ=64, BEAM=8, VOCAB=50257, STEP=5
#define BSZ   64
#define BEAM  8
#define VOCAB 50257
#define NSTEP 5
#define K     16
#define DIV_RATE 0.5f
#define SPLIT 8
#define N4    (VOCAB / 4)                  // 12564 float4s (+1 tail elem)
#define F4SEG ((N4 + SPLIT - 1) / SPLIT)   // 1571 f4/seg (last seg: 1567)
#define SEGCAP 512                         // per-seg LDS cap (proof bound 449)
#define ROWCAP 1024                        // per-row global candidate cap

typedef unsigned long long u64;
typedef unsigned u32;

// order-preserving float<->uint (monotone for all non-NaN)
__device__ __forceinline__ u32 f2s(float f) {
    u32 u = __float_as_uint(f);
    return (u & 0x80000000u) ? ~u : (u | 0x80000000u);
}
__device__ __forceinline__ float s2f(u32 s) {
    u32 u = (s & 0x80000000u) ? (s ^ 0x80000000u) : ~s;
    return __uint_as_float(u);
}

// wave(64)-wide max of a u64 key
__device__ __forceinline__ u64 wmax64(u64 k) {
#pragma unroll
    for (int off = 32; off > 0; off >>= 1) {
        u32 lo = __shfl_xor((u32)k, off, 64);
        u32 hi = __shfl_xor((u32)(k >> 32), off, 64);
        u64 o = ((u64)hi << 32) | lo;
        if (o > k) k = o;
    }
    return k;
}

// full bitonic sort of one u32 per lane across the 64-lane wave, ASCENDING
// (validated R3/R4: absmax 0). 21 compare-exchange steps.
__device__ __forceinline__ u32 bitonic64_asc(u32 v, int lane) {
#define BSTEP(K_, J_)                                                        \
    {                                                                        \
        u32 o = __shfl_xor(v, (J_), 64);                                     \
        bool tmin = ((lane & (J_)) == 0) == ((lane & (K_)) == 0);            \
        v = tmin ? (v < o ? v : o) : (v > o ? v : o);                        \
    }
    BSTEP(2, 1)
    BSTEP(4, 2)  BSTEP(4, 1)
    BSTEP(8, 4)  BSTEP(8, 2)  BSTEP(8, 1)
    BSTEP(16, 8) BSTEP(16, 4) BSTEP(16, 2) BSTEP(16, 1)
    BSTEP(32, 16) BSTEP(32, 8) BSTEP(32, 4) BSTEP(32, 2) BSTEP(32, 1)
    BSTEP(64, 32) BSTEP(64, 16) BSTEP(64, 8) BSTEP(64, 4) BSTEP(64, 2) BSTEP(64, 1)
#undef BSTEP
    return v;
}

// Phase 1: per (row, segment): burst-load 7 float4/thread into named regs
// (max MLP), T = exact 16th largest of the 256 per-thread maxima (subset
// property => T <= 16th largest segment element; only threads with m >= T
// can own candidates). Owners re-scan REGISTERS (values still live) and
// stage candidates in LDS; one global atomicAdd per block appends to the
// row's dense candidate list.
__global__ __launch_bounds__(256, 2) void collect(
    const float* __restrict__ lprobs, u64* __restrict__ rowbuf,
    int* __restrict__ rowcnt)
{
    const int tid  = threadIdx.x;
    const int lane = tid & 63;
    const int wave = tid >> 6;
    const int seg  = blockIdx.x;     // 0..7
    const int row  = blockIdx.y;     // 0..511

    const int s0 = seg * F4SEG;
    const int s1 = min(N4, s0 + F4SEG);
    const float4* rp4  = (const float4*)(lprobs + (size_t)row * VOCAB);
    const float4* base = rp4 + s0 + tid;

    // ---- burst: 6 unconditional + 1 predicated load, all independent ----
    // (min segment size 1567 >= 1536, so 0..5 are always in bounds)
    const int rem = s1 - s0 - 1536;            // 35 (segs 0-6) or 31 (seg 7)
    float4 a0 = base[0];
    float4 a1 = base[256];
    float4 a2 = base[512];
    float4 a3 = base[768];
    float4 a4 = base[1024];
    float4 a5 = base[1280];
    float4 a6 = make_float4(-INFINITY, -INFINITY, -INFINITY, -INFINITY);
    if (tid < rem) a6 = base[1536];
    float extra = -INFINITY;                   // vocab tail element 50256
    if (seg == SPLIT - 1 && tid == 0) extra = ((const float*)rp4)[VOCAB - 1];

#define MAX4(v) fmaxf(fmaxf((v).x, (v).y), fmaxf((v).z, (v).w))
    float m01 = fmaxf(MAX4(a0), MAX4(a1));
    float m23 = fmaxf(MAX4(a2), MAX4(a3));
    float m45 = fmaxf(MAX4(a4), MAX4(a5));
    float m6e = fmaxf(MAX4(a6), extra);
    float m = fmaxf(fmaxf(m01, m23), fmaxf(m45, m6e));
#undef MAX4

    // ---- threshold: exact 16th largest of the 256 maxima ----
    __shared__ u32 smax[64];
    __shared__ u64 sbuf[SEGCAP];
    __shared__ int scnt, sbase;
    if (tid == 0) scnt = 0;
    u32 v0 = bitonic64_asc(f2s(m), lane);
    if (lane >= 48) smax[wave * 16 + (lane - 48)] = v0;
    __syncthreads();
    // all 4 waves redundantly sort the 64 survivors (no wave0 serialization)
    u32 w0 = bitonic64_asc(smax[lane], lane);
    const float T = s2f(__shfl(w0, 48, 64));   // lane 48 = 16th largest

    // ---- owners (m >= T, exactly 16 threads) scan their REGISTERS ----
#define APPEND(vv, ei)                                                       \
    if ((vv) >= T) {                                                         \
        int p = atomicAdd(&scnt, 1);                                         \
        if (p < SEGCAP) sbuf[p] = ((u64)f2s(vv) << 32) | (u32)~(u32)(ei);    \
    }
    if (m >= T) {
        int b4 = 4 * (s0 + tid);
        APPEND(a0.x, b4 + 0)        APPEND(a0.y, b4 + 1)
        APPEND(a0.z, b4 + 2)        APPEND(a0.w, b4 + 3)
        APPEND(a1.x, b4 + 1024 + 0) APPEND(a1.y, b4 + 1024 + 1)
        APPEND(a1.z, b4 + 1024 + 2) APPEND(a1.w, b4 + 1024 + 3)
        APPEND(a2.x, b4 + 2048 + 0) APPEND(a2.y, b4 + 2048 + 1)
        APPEND(a2.z, b4 + 2048 + 2) APPEND(a2.w, b4 + 2048 + 3)
        APPEND(a3.x, b4 + 3072 + 0) APPEND(a3.y, b4 + 3072 + 1)
        APPEND(a3.z, b4 + 3072 + 2) APPEND(a3.w, b4 + 3072 + 3)
        APPEND(a4.x, b4 + 4096 + 0) APPEND(a4.y, b4 + 4096 + 1)
        APPEND(a4.z, b4 + 4096 + 2) APPEND(a4.w, b4 + 4096 + 3)
        APPEND(a5.x, b4 + 5120 + 0) APPEND(a5.y, b4 + 5120 + 1)
        APPEND(a5.z, b4 + 5120 + 2) APPEND(a5.w, b4 + 5120 + 3)
        APPEND(a6.x, b4 + 6144 + 0) APPEND(a6.y, b4 + 6144 + 1)   // -INF if !owner
        APPEND(a6.z, b4 + 6144 + 2) APPEND(a6.w, b4 + 6144 + 3)
        APPEND(extra, VOCAB - 1)                                   // -INF unless set
    }
#undef APPEND
    __syncthreads();

    // ---- one global append per block ----
    int n = min(scnt, SEGCAP);
    if (tid == 0) sbase = atomicAdd(&rowcnt[row], n);
    __syncthreads();
    if (tid < n) {
        int g = sbase + tid;
        if (g < ROWCAP) rowbuf[(size_t)row * ROWCAP + g] = sbuf[tid];
    }
}

// Phase 2: block b (of 64), wave j: exact sorted top-16 of row (b,j)'s
// candidate list (16 rounds of reg-max + wave-argmax); bias + sibling
// penalty; wave 0 selects the final top-16 of 128. (Candidate order is
// nondeterministic but keys are unique => deterministic output.)
__global__ __launch_bounds__(512) void merge_final(
    const u64* __restrict__ rowbuf, const int* __restrict__ rowcnt,
    const float* __restrict__ scores, const int* __restrict__ step_ptr,
    float* __restrict__ out)
{
    const int tid  = threadIdx.x;
    const int lane = tid & 63;
    const int j    = tid >> 6;       // beam 0..7
    const int b    = blockIdx.x;
    const int row  = b * BEAM + j;
    const int step = *step_ptr;

    __shared__ u64 rowkey[BEAM * K];
    __shared__ int rowvidx[BEAM * K];

    const int n = min(rowcnt[row], ROWCAP);
    u64 k[16];
#pragma unroll
    for (int i = 0; i < 16; ++i) {
        int p = lane + 64 * i;
        k[i] = (p < n) ? rowbuf[(size_t)row * ROWCAP + p] : 0ull;
    }

    u64 mine = 0;
#pragma unroll 1
    for (int it = 0; it < K; ++it) {
        u64 lm = k[0];
#pragma unroll
        for (int i = 1; i < 16; ++i) lm = (k[i] > lm) ? k[i] : lm;
        u64 mm = wmax64(lm);
        if (lane == it) mine = mm;
#pragma unroll
        for (int i = 0; i < 16; ++i) if (k[i] == mm) k[i] = 0;
    }

    float* out_s = out;
    float* out_i = out + BSZ * K;
    float* out_b = out + 2 * BSZ * K;

    if (step == 0) {
        // reference: top_k(lprobs[:,0,:]): idx%vocab=idx, idx//vocab=0
        if (j == 0 && lane < K) {
            out_s[b * K + lane] = s2f((u32)(mine >> 32));
            out_i[b * K + lane] = (float)(int)~(u32)mine;
            out_b[b * K + lane] = 0.0f;
        }
        return;
    }

    if (lane < K) {
        float v   = s2f((u32)(mine >> 32));
        float add = scores[row * NSTEP + step - 1];
        float sc  = v + add - (float)(lane + 1) * DIV_RATE;   // rank = lane
        int c = j * K + lane;
        rowkey[c]  = ((u64)f2s(sc) << 32) | (u32)(127 - c);   // lower c wins ties
        rowvidx[c] = (int)~(u32)mine;
    }
    __syncthreads();

    if (tid < 64) {
        u64 pa = rowkey[lane];
        u64 pb = rowkey[lane + 64];
        u64 m2 = 0;
#pragma unroll 1
        for (int it = 0; it < K; ++it) {
            u64 mm = wmax64(pa > pb ? pa : pb);
            if (lane == it) m2 = mm;
            if (pa == mm) pa = 0; else if (pb == mm) pb = 0;
        }
        if (lane < K) {
            int c = 127 - (int)(m2 & 0xFFFFFFFFull);
            out_s[b * K + lane] = s2f((u32)(m2 >> 32));
            out_i[b * K + lane] = (float)rowvidx[c];
            out_b[b * K + lane] = (float)(c >> 4);
        }
    }
}

extern "C" void kernel_launch(void* const* d_in, const int* in_sizes, int n_in,
                              void* d_out, int out_size, void* d_ws, size_t ws_size,
                              hipStream_t stream) {
    const float* lprobs = (const float*)d_in[0];
    const float* scores = (const float*)d_in[1];
    const int*   step   = (const int*)d_in[2];

    // ws layout: [0,4KB) row counters (512 ints), then row candidate buffers
    int* rowcnt = (int*)d_ws;
    u64* rowbuf = (u64*)((char*)d_ws + 4096);   // 512 * 1024 * 8 B = 4 MB

    hipMemsetAsync(d_ws, 0, 4096, stream);
    dim3 g1(SPLIT, BSZ * BEAM);
    collect<<<g1, 256, 0, stream>>>(lprobs, rowbuf, rowcnt);
    merge_final<<<BSZ, 512, 0, stream>>>(rowbuf, rowcnt, scores, step,
                                         (float*)d_out);
}

// Round 6
// 163.653 us; speedup vs baseline: 1.5062x; 1.1384x over previous
//
#include <hip/hip_runtime.h>
#include <math.h>

// Problem constants: BSZ=64, BEAM=8, VOCAB=50257, STEP=5
#define BSZ   64
#define BEAM  8
#define VOCAB 50257
#define NSTEP 5
#define K     16
#define DIV_RATE 0.5f
#define N4    (VOCAB / 4)        // 12564 float4s (+1 tail scalar)
#define SEGF4 (N4 / 2)           // 6282 float4 per half-row (exact split)
#define REM   (SEGF4 - 12 * 512) // 138: threads with tid<REM do a 13th load
#define SBUF_CAP 1024            // candidate LDS cap (proof bound 16*53=848)

typedef unsigned long long u64;
typedef unsigned u32;

// order-preserving float<->uint (monotone for all non-NaN)
__device__ __forceinline__ u32 f2s(float f) {
    u32 u = __float_as_uint(f);
    return (u & 0x80000000u) ? ~u : (u | 0x80000000u);
}
__device__ __forceinline__ float s2f(u32 s) {
    u32 u = (s & 0x80000000u) ? (s ^ 0x80000000u) : ~s;
    return __uint_as_float(u);
}

// wave(64)-wide max of a u64 key (validated R1-R5)
__device__ __forceinline__ u64 wmax64(u64 k) {
#pragma unroll
    for (int off = 32; off > 0; off >>= 1) {
        u32 lo = __shfl_xor((u32)k, off, 64);
        u32 hi = __shfl_xor((u32)(k >> 32), off, 64);
        u64 o = ((u64)hi << 32) | lo;
        if (o > k) k = o;
    }
    return k;
}

#define BSTEPS(X)                                                            \
    X(2, 1)                                                                  \
    X(4, 2)  X(4, 1)                                                         \
    X(8, 4)  X(8, 2)  X(8, 1)                                                \
    X(16, 8) X(16, 4) X(16, 2) X(16, 1)                                      \
    X(32, 16) X(32, 8) X(32, 4) X(32, 2) X(32, 1)                            \
    X(64, 32) X(64, 16) X(64, 8) X(64, 4) X(64, 2) X(64, 1)

// u32 ascending bitonic sort across 64 lanes (validated R3-R5)
__device__ __forceinline__ u32 bitonic64_asc(u32 v, int lane) {
#define BS32(K_, J_)                                                         \
    {                                                                        \
        u32 o = __shfl_xor(v, (J_), 64);                                     \
        bool tmin = ((lane & (J_)) == 0) == ((lane & (K_)) == 0);            \
        v = tmin ? (v < o ? v : o) : (v > o ? v : o);                        \
    }
    BSTEPS(BS32)
#undef BS32
    return v;
}

// u64 ascending bitonic sort across 64 lanes (same network, 2 shfl/step)
__device__ __forceinline__ u64 bitonic64_asc_u64(u64 v, int lane) {
#define BS64(K_, J_)                                                         \
    {                                                                        \
        u32 lo = __shfl_xor((u32)v, (J_), 64);                               \
        u32 hi = __shfl_xor((u32)(v >> 32), (J_), 64);                       \
        u64 o = ((u64)hi << 32) | lo;                                        \
        bool tmin = ((lane & (J_)) == 0) == ((lane & (K_)) == 0);            \
        v = tmin ? (v < o ? v : o) : (v > o ? v : o);                        \
    }
    BSTEPS(BS64)
#undef BS64
    return v;
}

// Phase 1: one block per (half-row). 13 independent float4 loads/thread kept
// live in registers; T = exact 16th largest of the 512 per-thread maxima
// (3-level bitonic tournament); owner threads (m >= T, exactly 16 modulo
// ties) scan registers into an LDS candidate list; wave 0 extracts the
// sorted half-row top-16 via chunked u64 bitonic and writes 16 keys densely.
// key = f2s(value)<<32 | ~vocab_idx (bias deferred: uniform per row).
__global__ __launch_bounds__(512, 4) void rowtop(
    const float* __restrict__ lprobs, u64* __restrict__ segk)
{
    const int tid  = threadIdx.x;
    const int lane = tid & 63;
    const int wave = tid >> 6;       // 0..7
    const int seg  = blockIdx.x;     // 0..1
    const int row  = blockIdx.y;     // 0..511

    const float4* rp4  = (const float4*)(lprobs + (size_t)row * VOCAB);
    const float4* base = rp4 + seg * SEGF4 + tid;

    // ---- burst: 12 unconditional + 1 predicated, all independent ----
    float4 a0  = base[0];
    float4 a1  = base[512];
    float4 a2  = base[1024];
    float4 a3  = base[1536];
    float4 a4  = base[2048];
    float4 a5  = base[2560];
    float4 a6  = base[3072];
    float4 a7  = base[3584];
    float4 a8  = base[4096];
    float4 a9  = base[4608];
    float4 a10 = base[5120];
    float4 a11 = base[5632];
    float4 a12 = make_float4(-INFINITY, -INFINITY, -INFINITY, -INFINITY);
    if (tid < REM) a12 = base[6144];
    float extra = -INFINITY;                    // vocab tail element 50256
    if (seg == 1 && tid == 0) extra = ((const float*)rp4)[VOCAB - 1];

#define MAX4(v) fmaxf(fmaxf((v).x, (v).y), fmaxf((v).z, (v).w))
    float m = fmaxf(
        fmaxf(fmaxf(fmaxf(MAX4(a0), MAX4(a1)), fmaxf(MAX4(a2), MAX4(a3))),
              fmaxf(fmaxf(MAX4(a4), MAX4(a5)), fmaxf(MAX4(a6), MAX4(a7)))),
        fmaxf(fmaxf(fmaxf(MAX4(a8), MAX4(a9)), fmaxf(MAX4(a10), MAX4(a11))),
              fmaxf(MAX4(a12), extra)));
#undef MAX4

    __shared__ u32 smax[128];        // 8 waves x top-16 maxima
    __shared__ u32 sfin[32];         // 2 x top-16 finalists
    __shared__ u32 sT;
    __shared__ u64 sbuf[SBUF_CAP];
    __shared__ int scnt;
    if (tid == 0) scnt = 0;

    // ---- level 1: per-wave top-16 of lane maxima ----
    u32 v0 = bitonic64_asc(f2s(m), lane);
    if (lane >= 48) smax[wave * 16 + (lane - 48)] = v0;
    __syncthreads();

    // ---- level 2: waves 0,1 each reduce 64 survivors -> 16 finalists ----
    if (wave < 2) {
        u32 w = bitonic64_asc(smax[wave * 64 + lane], lane);
        if (lane >= 48) sfin[wave * 16 + (lane - 48)] = w;
    }
    __syncthreads();

    // ---- level 3: wave 0 sorts 32 finalists; lane 48 = 16th largest ----
    if (wave == 0) {
        u32 w = bitonic64_asc(lane < 32 ? sfin[lane] : 0u, lane);
        if (lane == 48) sT = w;
    }
    __syncthreads();
    const float T = s2f(sT);

    // ---- owners (m >= T) scan their REGISTERS into LDS ----
#define APPEND(vv, ei)                                                       \
    if ((vv) >= T) {                                                         \
        int p = atomicAdd(&scnt, 1);                                         \
        if (p < SBUF_CAP) sbuf[p] = ((u64)f2s(vv) << 32) | (u32)~(u32)(ei);  \
    }
#define APP4(av, c4)                                                         \
    {                                                                        \
        int b4 = 4 * (seg * SEGF4 + (c4) * 512 + tid);                       \
        APPEND((av).x, b4 + 0) APPEND((av).y, b4 + 1)                        \
        APPEND((av).z, b4 + 2) APPEND((av).w, b4 + 3)                        \
    }
    if (m >= T) {
        APP4(a0, 0)  APP4(a1, 1)  APP4(a2, 2)   APP4(a3, 3)
        APP4(a4, 4)  APP4(a5, 5)  APP4(a6, 6)   APP4(a7, 7)
        APP4(a8, 8)  APP4(a9, 9)  APP4(a10, 10) APP4(a11, 11)
        APP4(a12, 12)                              // -INF lanes never pass
        APPEND(extra, VOCAB - 1)                   // -INF unless set
    }
#undef APP4
#undef APPEND
    __syncthreads();

    // ---- wave 0: sorted top-16 of candidates via chunked u64 bitonic ----
    if (wave == 0) {
        const int n = min(scnt, SBUF_CAP);        // n >= 16 always
        u64 run = 0;
        for (int b0 = 0; b0 < n; b0 += 48) {
            u64 v = run;                          // lanes 48..63 keep top-16
            if (lane < 48) { int p = b0 + lane; v = (p < n) ? sbuf[p] : 0; }
            v = bitonic64_asc_u64(v, lane);
            run = (lane >= 48) ? v : 0;
        }
        if (lane >= 48) {                         // rank 0 = best
            int r = 63 - lane;
            segk[((size_t)row * 2 + seg) * K + r] = run;
        }
    }
}

// Phase 2: block b, wave j: merge beam j's two sorted 16-lists (one u64
// bitonic over 32 keys + 32 zero pads; rank = lane position), apply bias +
// sibling penalty, wave 0 runs the validated 128->16 extraction.
__global__ __launch_bounds__(512) void finalize(
    const u64* __restrict__ segk, const float* __restrict__ scores,
    const int* __restrict__ step_ptr, float* __restrict__ out)
{
    const int tid  = threadIdx.x;
    const int lane = tid & 63;
    const int j    = tid >> 6;       // beam 0..7
    const int b    = blockIdx.x;
    const int row  = b * BEAM + j;
    const int step = *step_ptr;

    __shared__ u64 fkey[BEAM * K];
    __shared__ int fvid[BEAM * K];

    // merged row top-16: sort 32 real keys (unique: disjoint vocab halves)
    u64 v = (lane < 32) ? segk[(size_t)row * 32 + lane] : 0ull;
    v = bitonic64_asc_u64(v, lane);
    // lanes 48..63 hold the row top-16 ascending; rank r = 63 - lane

    float* out_s = out;
    float* out_i = out + BSZ * K;
    float* out_b = out + 2 * BSZ * K;

    if (step == 0) {
        // reference: top_k(lprobs[:,0,:]): idx%vocab=idx, idx//vocab=0
        if (j == 0 && lane >= 48) {
            int r = 63 - lane;
            out_s[b * K + r] = s2f((u32)(v >> 32));
            out_i[b * K + r] = (float)(int)~(u32)v;
            out_b[b * K + r] = 0.0f;
        }
        return;
    }

    if (lane >= 48) {
        int r = 63 - lane;
        float val = s2f((u32)(v >> 32));
        float add = scores[row * NSTEP + step - 1];
        float sc  = val + add - (float)(r + 1) * DIV_RATE;
        int c = j * K + r;
        fkey[c] = ((u64)f2s(sc) << 32) | (u32)(127 - c);  // lower c wins ties
        fvid[c] = (int)~(u32)v;
    }
    __syncthreads();

    if (tid < 64) {
        u64 pa = fkey[lane];
        u64 pb = fkey[lane + 64];
        u64 m2 = 0;
#pragma unroll 1
        for (int it = 0; it < K; ++it) {
            u64 mm = wmax64(pa > pb ? pa : pb);
            if (lane == it) m2 = mm;
            if (pa == mm) pa = 0; else if (pb == mm) pb = 0;
        }
        if (lane < K) {
            int c = 127 - (int)(m2 & 0xFFFFFFFFull);
            out_s[b * K + lane] = s2f((u32)(m2 >> 32));
            out_i[b * K + lane] = (float)fvid[c];
            out_b[b * K + lane] = (float)(c >> 4);
        }
    }
}

extern "C" void kernel_launch(void* const* d_in, const int* in_sizes, int n_in,
                              void* d_out, int out_size, void* d_ws, size_t ws_size,
                              hipStream_t stream) {
    const float* lprobs = (const float*)d_in[0];
    const float* scores = (const float*)d_in[1];
    const int*   step   = (const int*)d_in[2];

    u64* segk = (u64*)d_ws;   // 512 rows * 2 segs * 16 keys * 8 B = 128 KB

    dim3 g1(2, BSZ * BEAM);
    rowtop<<<g1, 512, 0, stream>>>(lprobs, segk);
    finalize<<<BSZ, 512, 0, stream>>>(segk, scores, step, (float*)d_out);
}